// Round 1
// baseline (215.814 us; speedup 1.0000x reference)
//
#include <hip/hip_runtime.h>

// ExplaiNN inference on MFMA (bf16 matrix cores, f32 accumulate). 2 kernels:
// conv_mfma: implicit-GEMM conv + BN1 + ReLU + maxpool10 -> pooled[b][g][p] bf16
//            conv_w -> Wl[12][304][8] bf16 transform done in-kernel (prep_all folded in).
//            Also: out = cls_b init (stream-ordered before mlp atomics) + 256B zero pad
//            after pooled (mlp overreads <=56B; pad must be finite, ws is NaN-poisoned).
// mlp_mfma:  per-group GEMM [128b x 112h x 128i] + BN2/ReLU + W2-dot + BN3/ReLU,
//            W1 -> B-fragment LDS transform in-kernel (W1b intermediate eliminated),
//            classifier fused: out[b][c] += h2 * cls_w[c][g] via atomicAdd (300 adds/loc).

typedef unsigned short ushort_t;
typedef short short8 __attribute__((ext_vector_type(8)));
typedef float floatx4 __attribute__((ext_vector_type(4)));

constexpr float EPSf = 1e-5f;

__device__ __forceinline__ ushort_t f2bf(float f) {
    unsigned u = __float_as_uint(f);
    unsigned r = (u + 0x7FFFu + ((u >> 16) & 1u)) >> 16;   // round-to-nearest-even
    return (ushort_t)r;
}

// ---------------- Stage 1: conv via MFMA ----------------
// Window q=0: p 0..51 (4 M-tiles), q=1: p 52..99 (3 M-tiles). X0 = x_pad origin of LDS window.
// C[m=p][n=g] = sum_k A[m][k] B[k][n]; A[m][(c,t)] = x_pad[c][10(p)+d+t]; max over d=0..9.
__global__ __launch_bounds__(256, 2) void conv_mfma(
    const float* __restrict__ x, const float* __restrict__ conv_w,
    const float* __restrict__ conv_b, const float* __restrict__ g1, const float* __restrict__ be1,
    const float* __restrict__ m1, const float* __restrict__ v1,
    ushort_t* __restrict__ pooled, const float* __restrict__ cls_b, float* __restrict__ out)
{
    __shared__ ushort_t Wl[12 * 304 * 8];      // 58368 B, [kc][g][8]
    __shared__ ushort_t xl[16 * 552];          // 17664 B, [(phi*4+c)][552], phase-shifted copies
    __shared__ float A1s[304], B1s[304];

    const int tid = threadIdx.x;
    const int b = blockIdx.x, q = blockIdx.y;
    const int X0 = q * 520;                     // x_pad coordinate of xl[.][0]

    // classifier accumulator init: out = cls_b. Stream order => lands before mlp's atomics.
    if (tid == 0) out[b * 2 + q] = cls_b[q];
    // zero the 256B pad after pooled (mlp's kc=13..15 A-frag reads spill past row end;
    // B-frags there are zero, but poison could be NaN/Inf and NaN*0 = NaN).
    if (b == 0 && q == 0 && tid < 16) {
        uint4 z = {0, 0, 0, 0};
        *(uint4*)&pooled[7680000 + tid * 8] = z;
    }

    // stage x (f32 global) -> 4 phase copies bf16 in LDS; copy phi elem i = x_pad[X0+i+phi]
    for (int u = tid; u < 16 * 276; u += 256) { // uint = 2 bf16
        int iu = u % 276, r = u / 276;
        int c = r & 3, phi = r >> 2;
        int gi = X0 + 2 * iu + phi - 9;         // x index of low element
        const float* xb = x + b * 4000 + c * 1000;
        float v0 = ((unsigned)gi < 1000u) ? xb[gi] : 0.f;
        float v1_ = ((unsigned)(gi + 1) < 1000u) ? xb[gi + 1] : 0.f;
        ((unsigned*)xl)[u] = (unsigned)f2bf(v0) | ((unsigned)f2bf(v1_) << 16);
    }
    // weights: conv_w f32 -> Wl bf16 in-kernel (prep_all folded in).
    // chunk u = kc*304+g covers taps k=kc*8..kc*8+7; 24=3*8 so c is constant per chunk.
    for (int u = tid; u < 3648; u += 256) {
        int g = u % 304, kc = u / 304;
        int k0 = kc * 8, c = k0 / 24, tt0 = k0 - c * 24;
        ushort_t tmp[8];
        if (g < 300) {
            const float* src = conv_w + g * 76 + c * 19;
#pragma unroll
            for (int j = 0; j < 8; ++j) {
                int tt = tt0 + j;
                tmp[j] = (tt < 19) ? f2bf(src[tt]) : (ushort_t)0;
            }
        } else {
#pragma unroll
            for (int j = 0; j < 8; ++j) tmp[j] = 0;
        }
        uint4 o;
        o.x = (unsigned)tmp[0] | ((unsigned)tmp[1] << 16);
        o.y = (unsigned)tmp[2] | ((unsigned)tmp[3] << 16);
        o.z = (unsigned)tmp[4] | ((unsigned)tmp[5] << 16);
        o.w = (unsigned)tmp[6] | ((unsigned)tmp[7] << 16);
        *(uint4*)&Wl[u * 8] = o;                // consecutive threads -> consecutive 16B
    }
    for (int i = tid; i < 304; i += 256) {
        if (i < 300) {
            float A = g1[i] * rsqrtf(v1[i] + EPSf);
            A1s[i] = A;
            B1s[i] = (conv_b[i] - m1[i]) * A + be1[i];
        } else { A1s[i] = 0.f; B1s[i] = 0.f; }
    }
    __syncthreads();

    const int w = tid >> 6, lane = tid & 63;
    if (q == 1 && w == 3) return;               // 3 tiles in window 1; no barriers after this
    const int p0 = q ? (52 + w * 16) : (w * 16);
    const int pmax = q ? 99 : 51;
    const int row = lane & 15, quad = lane >> 4;
    const int p_r = p0 + row;
    const int prc = (p_r < pmax) ? p_r : pmax;  // clamp keeps LDS reads in window (rows masked at store)

    // A fragments cached for all (d, s): lane holds A[row][32s+quad*8 .. +7]
    uint4 af[10][3];
#pragma unroll
    for (int s = 0; s < 3; ++s) {
        int k0 = s * 32 + quad * 8;
        int c = k0 / 24, t0 = k0 - c * 24;
        int base0 = 10 * prc + t0 - X0;         // local window coords, max 542 (q0) / 502 (q1)
#pragma unroll
        for (int d = 0; d < 10; ++d) {
            int local = base0 + d;
            int phi = local & 3, bi = local - phi;
            const ushort_t* p = &xl[(phi * 4 + c) * 552 + bi];  // 8B-aligned
            uint2 lo = *(const uint2*)p;
            uint2 hi = *(const uint2*)(p + 4);
            af[d][s] = (uint4){lo.x, lo.y, hi.x, hi.y};
        }
    }

    for (int gt = 0; gt < 19; ++gt) {
        short8 bf[3];
#pragma unroll
        for (int s = 0; s < 3; ++s) {
            uint4 t4 = *(const uint4*)&Wl[(((s * 4 + quad) * 304) + gt * 16 + row) * 8];
            bf[s] = __builtin_bit_cast(short8, t4);
        }
        const float a1v = A1s[gt * 16 + row], b1v = B1s[gt * 16 + row];
        floatx4 mx = {0.f, 0.f, 0.f, 0.f};     // ReLU floor
#pragma unroll
        for (int d = 0; d < 10; ++d) {
            floatx4 acc = {0.f, 0.f, 0.f, 0.f};
#pragma unroll
            for (int s = 0; s < 3; ++s)
                acc = __builtin_amdgcn_mfma_f32_16x16x32_bf16(
                    __builtin_bit_cast(short8, af[d][s]), bf[s], acc, 0, 0, 0);
#pragma unroll
            for (int r = 0; r < 4; ++r)
                mx[r] = fmaxf(mx[r], fmaf(acc[r], a1v, b1v));
        }
        const int g = gt * 16 + row;            // C col = lane&15
        const int pr0 = p0 + quad * 4;          // C rows = quad*4 + r
        if (g < 300 && pr0 + 3 <= pmax) {
            ushort4 o = make_ushort4(f2bf(mx[0]), f2bf(mx[1]), f2bf(mx[2]), f2bf(mx[3]));
            *(ushort4*)&pooled[((size_t)b * 300 + g) * 100 + pr0] = o;
        }
    }
}

// ---------------- Stage 2: grouped MLP via MFMA + fused classifier ----------------
// grid 608: blk&7 = XCD slice, 38 g each, 2 b-halves per g on the same slice.
__global__ __launch_bounds__(256, 2) void mlp_mfma(
    const ushort_t* __restrict__ pooled, const float* __restrict__ W1,
    const float* __restrict__ b1, const float* __restrict__ g2, const float* __restrict__ be2,
    const float* __restrict__ m2, const float* __restrict__ v2,
    const float* __restrict__ W2, const float* __restrict__ b2,
    const float* __restrict__ g3, const float* __restrict__ be3,
    const float* __restrict__ m3, const float* __restrict__ v3,
    const float* __restrict__ cls_w, float* __restrict__ out)
{
    __shared__ ushort_t W1l[16 * 112 * 8];     // 28672 B, [kc][h][8]
    __shared__ ushort_t pl[128 * 128];         // 32768 B, [bl][chunk^(bl&7)][8]
    __shared__ float A2s[112], C2s[112], w2sl[112];
    __shared__ float sA3, sC3;

    const int tid = threadIdx.x;
    const int blk = blockIdx.x;
    const int xcd = blk & 7, j = blk >> 3;
    const int g = xcd * 38 + (j >> 1);
    if (g >= 300) return;
    const int b0 = (j & 1) * 128;

    const float cw0 = cls_w[g], cw1 = cls_w[300 + g];   // wave-uniform scalar loads

    // W1 f32 -> B-fragment LDS image (W1b intermediate eliminated; 2 blocks/g share XCD L2)
    for (int vv = tid; vv < 3584; vv += 256) {
        int jj = vv & 1, r = vv >> 1, h = r % 112, kc = r / 112;
        int i0 = kc * 8 + jj * 4;
        ushort4 o = make_ushort4(0, 0, 0, 0);
        if (h < 100 && i0 <= 96) {
            float4 wv = *(const float4*)&W1[(size_t)g * 10000 + h * 100 + i0];
            o = make_ushort4(f2bf(wv.x), f2bf(wv.y), f2bf(wv.z), f2bf(wv.w));
        }
        *(ushort4*)&W1l[((kc * 112) + h) * 8 + jj * 4] = o;   // consecutive threads -> consecutive 8B
    }
    for (int qq = tid; qq < 128 * 16; qq += 256) {
        int bl = qq >> 4, kc = qq & 15;
        const ushort_t* src = pooled + ((size_t)(b0 + bl) * 300 + g) * 100 + kc * 8;
        uint2 lo = *(const uint2*)src;          // rows 200B apart: 8B-aligned
        uint2 hi = *(const uint2*)(src + 4);    // i>=100 spills into next row / zero pad (finite, x0 by W pad)
        int swz = kc ^ (bl & 7);
        *(uint4*)&pl[((bl * 16) + swz) * 8] = (uint4){lo.x, lo.y, hi.x, hi.y};
    }
    if (tid < 112) {
        float a2 = 0.f, c2 = 0.f, w2v = 0.f;
        if (tid < 100) {
            int qq = g * 100 + tid;
            a2 = g2[qq] * rsqrtf(v2[qq] + EPSf);
            c2 = (b1[qq] - m2[qq]) * a2 + be2[qq];
            w2v = W2[qq];
        }
        A2s[tid] = a2; C2s[tid] = c2; w2sl[tid] = w2v;
    }
    if (tid == 0) {
        float a3 = g3[g] * rsqrtf(v3[g] + EPSf);
        sA3 = a3; sC3 = (b2[g] - m3[g]) * a3 + be3[g];
    }
    __syncthreads();

    const int w = tid >> 6, lane = tid & 63;
    const int col = lane & 15, quad = lane >> 4;

    short8 bfr[7][4];                          // all B-frags cached (112 VGPR)
#pragma unroll
    for (int nt = 0; nt < 7; ++nt)
#pragma unroll
        for (int s = 0; s < 4; ++s) {
            uint4 t4 = *(const uint4*)&W1l[(((s * 4 + quad) * 112) + nt * 16 + col) * 8];
            bfr[nt][s] = __builtin_bit_cast(short8, t4);
        }

#pragma unroll
    for (int mi = 0; mi < 2; ++mi) {
        const int mt = w * 2 + mi;
        const int bl = mt * 16 + col;          // A row
        uint4 afr[4];
#pragma unroll
        for (int s = 0; s < 4; ++s) {
            int kc = s * 4 + quad;
            afr[s] = *(const uint4*)&pl[((bl * 16) + (kc ^ (bl & 7))) * 8];
        }
        float run0 = 0.f, run1 = 0.f, run2 = 0.f, run3 = 0.f;
#pragma unroll
        for (int nt = 0; nt < 7; ++nt) {
            floatx4 acc = {0.f, 0.f, 0.f, 0.f};
#pragma unroll
            for (int s = 0; s < 4; ++s)
                acc = __builtin_amdgcn_mfma_f32_16x16x32_bf16(
                    __builtin_bit_cast(short8, afr[s]), bfr[nt][s], acc, 0, 0, 0);
            const float a2v = A2s[nt * 16 + col], c2v = C2s[nt * 16 + col], w2v = w2sl[nt * 16 + col];
            run0 += fmaxf(fmaf(acc[0], a2v, c2v), 0.f) * w2v;
            run1 += fmaxf(fmaf(acc[1], a2v, c2v), 0.f) * w2v;
            run2 += fmaxf(fmaf(acc[2], a2v, c2v), 0.f) * w2v;
            run3 += fmaxf(fmaf(acc[3], a2v, c2v), 0.f) * w2v;
        }
#pragma unroll
        for (int m = 1; m <= 8; m <<= 1) {     // sum over the 16 h-cols
            run0 += __shfl_xor(run0, m, 64);
            run1 += __shfl_xor(run1, m, 64);
            run2 += __shfl_xor(run2, m, 64);
            run3 += __shfl_xor(run3, m, 64);
        }
        if (col == 0) {                        // fused classifier: h2 * cls_w, 300 adds/location
            const int bb = b0 + mt * 16 + quad * 4;
            float v0 = fmaxf(fmaf(run0, sA3, sC3), 0.f);
            float v1_ = fmaxf(fmaf(run1, sA3, sC3), 0.f);
            float v2_ = fmaxf(fmaf(run2, sA3, sC3), 0.f);
            float v3_ = fmaxf(fmaf(run3, sA3, sC3), 0.f);
            atomicAdd(&out[(bb + 0) * 2 + 0], v0 * cw0);
            atomicAdd(&out[(bb + 0) * 2 + 1], v0 * cw1);
            atomicAdd(&out[(bb + 1) * 2 + 0], v1_ * cw0);
            atomicAdd(&out[(bb + 1) * 2 + 1], v1_ * cw1);
            atomicAdd(&out[(bb + 2) * 2 + 0], v2_ * cw0);
            atomicAdd(&out[(bb + 2) * 2 + 1], v2_ * cw1);
            atomicAdd(&out[(bb + 3) * 2 + 0], v3_ * cw0);
            atomicAdd(&out[(bb + 3) * 2 + 1], v3_ * cw1);
        }
    }
}

extern "C" void kernel_launch(void* const* d_in, const int* in_sizes, int n_in,
                              void* d_out, int out_size, void* d_ws, size_t ws_size,
                              hipStream_t stream) {
    const float* x      = (const float*)d_in[0];
    const float* conv_w = (const float*)d_in[1];
    const float* conv_b = (const float*)d_in[2];
    const float* bn1_g  = (const float*)d_in[3];
    const float* bn1_b  = (const float*)d_in[4];
    const float* bn1_m  = (const float*)d_in[5];
    const float* bn1_v  = (const float*)d_in[6];
    const float* W1     = (const float*)d_in[7];
    const float* b1     = (const float*)d_in[8];
    const float* bn2_g  = (const float*)d_in[9];
    const float* bn2_b  = (const float*)d_in[10];
    const float* bn2_m  = (const float*)d_in[11];
    const float* bn2_v  = (const float*)d_in[12];
    const float* W2     = (const float*)d_in[13];
    const float* b2     = (const float*)d_in[14];
    const float* bn3_g  = (const float*)d_in[15];
    const float* bn3_b  = (const float*)d_in[16];
    const float* bn3_m  = (const float*)d_in[17];
    const float* bn3_v  = (const float*)d_in[18];
    const float* cls_w  = (const float*)d_in[19];
    const float* cls_b  = (const float*)d_in[20];

    // workspace: pooled only — 15,360,000 B + 256 B zero pad (written by conv_mfma)
    ushort_t* pooled = (ushort_t*)d_ws;

    conv_mfma<<<dim3(256, 2), 256, 0, stream>>>(
        x, conv_w, conv_b, bn1_g, bn1_b, bn1_m, bn1_v, pooled, cls_b, (float*)d_out);

    mlp_mfma<<<dim3(608), 256, 0, stream>>>(
        pooled, W1, b1, bn2_g, bn2_b, bn2_m, bn2_v, W2, b2,
        bn3_g, bn3_b, bn3_m, bn3_v, cls_w, (float*)d_out);
}

// Round 2
// 162.811 us; speedup vs baseline: 1.3255x; 1.3255x over previous
//
#include <hip/hip_runtime.h>

// ExplaiNN inference on MFMA (bf16 matrix cores, f32 accumulate). 3 kernels:
// conv_mfma: implicit-GEMM conv + BN1 + ReLU + maxpool10 -> pooled[b][g][p] bf16
//            conv_w -> Wl[12][304][8] bf16 transform done in-kernel (prep folded in).
//            Also zeroes a 256B pad after pooled (mlp overreads <=56B; ws is NaN-poisoned).
// mlp_mfma:  per-group GEMM [128b x 112h x 128i] + BN2/ReLU + W2-dot + BN3/ReLU -> h2ws[g][b]
//            W1 -> B-fragment LDS transform in-kernel (W1b intermediate eliminated).
// classifier: h2 @ cls_w^T + cls_b -> out[256][2] f32 (plain stores; atomicAdd fusion
//            REVERTED: 300-way same-cacheline device atomics serialized at ~16ns/RMW = 76us).

typedef unsigned short ushort_t;
typedef short short8 __attribute__((ext_vector_type(8)));
typedef float floatx4 __attribute__((ext_vector_type(4)));

constexpr float EPSf = 1e-5f;

__device__ __forceinline__ ushort_t f2bf(float f) {
    unsigned u = __float_as_uint(f);
    unsigned r = (u + 0x7FFFu + ((u >> 16) & 1u)) >> 16;   // round-to-nearest-even
    return (ushort_t)r;
}

// ---------------- Stage 1: conv via MFMA ----------------
// Window q=0: p 0..51 (4 M-tiles), q=1: p 52..99 (3 M-tiles). X0 = x_pad origin of LDS window.
// C[m=p][n=g] = sum_k A[m][k] B[k][n]; A[m][(c,t)] = x_pad[c][10(p)+d+t]; max over d=0..9.
__global__ __launch_bounds__(256, 2) void conv_mfma(
    const float* __restrict__ x, const float* __restrict__ conv_w,
    const float* __restrict__ conv_b, const float* __restrict__ g1, const float* __restrict__ be1,
    const float* __restrict__ m1, const float* __restrict__ v1,
    ushort_t* __restrict__ pooled)
{
    __shared__ ushort_t Wl[12 * 304 * 8];      // 58368 B, [kc][g][8]
    __shared__ ushort_t xl[16 * 552];          // 17664 B, [(phi*4+c)][552], phase-shifted copies
    __shared__ float A1s[304], B1s[304];

    const int tid = threadIdx.x;
    const int b = blockIdx.x, q = blockIdx.y;
    const int X0 = q * 520;                     // x_pad coordinate of xl[.][0]

    // zero the 256B pad after pooled (mlp's kc=13..15 A-frag reads spill past row end;
    // B-frags there are zero, but poison could be NaN/Inf and NaN*0 = NaN).
    if (b == 0 && q == 0 && tid < 16) {
        uint4 z = {0, 0, 0, 0};
        *(uint4*)&pooled[7680000 + tid * 8] = z;
    }

    // stage x (f32 global) -> 4 phase copies bf16 in LDS; copy phi elem i = x_pad[X0+i+phi]
    for (int u = tid; u < 16 * 276; u += 256) { // uint = 2 bf16
        int iu = u % 276, r = u / 276;
        int c = r & 3, phi = r >> 2;
        int gi = X0 + 2 * iu + phi - 9;         // x index of low element
        const float* xb = x + b * 4000 + c * 1000;
        float v0 = ((unsigned)gi < 1000u) ? xb[gi] : 0.f;
        float v1_ = ((unsigned)(gi + 1) < 1000u) ? xb[gi + 1] : 0.f;
        ((unsigned*)xl)[u] = (unsigned)f2bf(v0) | ((unsigned)f2bf(v1_) << 16);
    }
    // weights: conv_w f32 -> Wl bf16 in-kernel (prep folded in).
    // chunk u = kc*304+g covers taps k=kc*8..kc*8+7; 24=3*8 so c is constant per chunk.
    for (int u = tid; u < 3648; u += 256) {
        int g = u % 304, kc = u / 304;
        int k0 = kc * 8, c = k0 / 24, tt0 = k0 - c * 24;
        ushort_t tmp[8];
        if (g < 300) {
            const float* src = conv_w + g * 76 + c * 19;
#pragma unroll
            for (int j = 0; j < 8; ++j) {
                int tt = tt0 + j;
                tmp[j] = (tt < 19) ? f2bf(src[tt]) : (ushort_t)0;
            }
        } else {
#pragma unroll
            for (int j = 0; j < 8; ++j) tmp[j] = 0;
        }
        uint4 o;
        o.x = (unsigned)tmp[0] | ((unsigned)tmp[1] << 16);
        o.y = (unsigned)tmp[2] | ((unsigned)tmp[3] << 16);
        o.z = (unsigned)tmp[4] | ((unsigned)tmp[5] << 16);
        o.w = (unsigned)tmp[6] | ((unsigned)tmp[7] << 16);
        *(uint4*)&Wl[u * 8] = o;                // consecutive threads -> consecutive 16B
    }
    for (int i = tid; i < 304; i += 256) {
        if (i < 300) {
            float A = g1[i] * rsqrtf(v1[i] + EPSf);
            A1s[i] = A;
            B1s[i] = (conv_b[i] - m1[i]) * A + be1[i];
        } else { A1s[i] = 0.f; B1s[i] = 0.f; }
    }
    __syncthreads();

    const int w = tid >> 6, lane = tid & 63;
    if (q == 1 && w == 3) return;               // 3 tiles in window 1; no barriers after this
    const int p0 = q ? (52 + w * 16) : (w * 16);
    const int pmax = q ? 99 : 51;
    const int row = lane & 15, quad = lane >> 4;
    const int p_r = p0 + row;
    const int prc = (p_r < pmax) ? p_r : pmax;  // clamp keeps LDS reads in window (rows masked at store)

    // A fragments cached for all (d, s): lane holds A[row][32s+quad*8 .. +7]
    uint4 af[10][3];
#pragma unroll
    for (int s = 0; s < 3; ++s) {
        int k0 = s * 32 + quad * 8;
        int c = k0 / 24, t0 = k0 - c * 24;
        int base0 = 10 * prc + t0 - X0;         // local window coords, max 542 (q0) / 502 (q1)
#pragma unroll
        for (int d = 0; d < 10; ++d) {
            int local = base0 + d;
            int phi = local & 3, bi = local - phi;
            const ushort_t* p = &xl[(phi * 4 + c) * 552 + bi];  // 8B-aligned
            uint2 lo = *(const uint2*)p;
            uint2 hi = *(const uint2*)(p + 4);
            af[d][s] = (uint4){lo.x, lo.y, hi.x, hi.y};
        }
    }

    for (int gt = 0; gt < 19; ++gt) {
        short8 bf[3];
#pragma unroll
        for (int s = 0; s < 3; ++s) {
            uint4 t4 = *(const uint4*)&Wl[(((s * 4 + quad) * 304) + gt * 16 + row) * 8];
            bf[s] = __builtin_bit_cast(short8, t4);
        }
        const float a1v = A1s[gt * 16 + row], b1v = B1s[gt * 16 + row];
        floatx4 mx = {0.f, 0.f, 0.f, 0.f};     // ReLU floor
#pragma unroll
        for (int d = 0; d < 10; ++d) {
            floatx4 acc = {0.f, 0.f, 0.f, 0.f};
#pragma unroll
            for (int s = 0; s < 3; ++s)
                acc = __builtin_amdgcn_mfma_f32_16x16x32_bf16(
                    __builtin_bit_cast(short8, af[d][s]), bf[s], acc, 0, 0, 0);
#pragma unroll
            for (int r = 0; r < 4; ++r)
                mx[r] = fmaxf(mx[r], fmaf(acc[r], a1v, b1v));
        }
        const int g = gt * 16 + row;            // C col = lane&15
        const int pr0 = p0 + quad * 4;          // C rows = quad*4 + r
        if (g < 300 && pr0 + 3 <= pmax) {
            ushort4 o = make_ushort4(f2bf(mx[0]), f2bf(mx[1]), f2bf(mx[2]), f2bf(mx[3]));
            *(ushort4*)&pooled[((size_t)b * 300 + g) * 100 + pr0] = o;
        }
    }
}

// ---------------- Stage 2: grouped MLP via MFMA ----------------
// grid 608: blk&7 = XCD slice, 38 g each, 2 b-halves per g on the same slice.
__global__ __launch_bounds__(256, 2) void mlp_mfma(
    const ushort_t* __restrict__ pooled, const float* __restrict__ W1,
    const float* __restrict__ b1, const float* __restrict__ g2, const float* __restrict__ be2,
    const float* __restrict__ m2, const float* __restrict__ v2,
    const float* __restrict__ W2, const float* __restrict__ b2,
    const float* __restrict__ g3, const float* __restrict__ be3,
    const float* __restrict__ m3, const float* __restrict__ v3,
    float* __restrict__ h2ws)
{
    __shared__ ushort_t W1l[16 * 112 * 8];     // 28672 B, [kc][h][8]
    __shared__ ushort_t pl[128 * 128];         // 32768 B, [bl][chunk^(bl&7)][8]
    __shared__ float A2s[112], C2s[112], w2sl[112];
    __shared__ float sA3, sC3;

    const int tid = threadIdx.x;
    const int blk = blockIdx.x;
    const int xcd = blk & 7, j = blk >> 3;
    const int g = xcd * 38 + (j >> 1);
    if (g >= 300) return;
    const int b0 = (j & 1) * 128;

    // W1 f32 -> B-fragment LDS image (W1b intermediate eliminated; 2 blocks/g share XCD L2)
    for (int vv = tid; vv < 3584; vv += 256) {
        int jj = vv & 1, r = vv >> 1, h = r % 112, kc = r / 112;
        int i0 = kc * 8 + jj * 4;
        ushort4 o = make_ushort4(0, 0, 0, 0);
        if (h < 100 && i0 <= 96) {
            float4 wv = *(const float4*)&W1[(size_t)g * 10000 + h * 100 + i0];
            o = make_ushort4(f2bf(wv.x), f2bf(wv.y), f2bf(wv.z), f2bf(wv.w));
        }
        *(ushort4*)&W1l[((kc * 112) + h) * 8 + jj * 4] = o;   // consecutive threads -> consecutive 8B
    }
    for (int qq = tid; qq < 128 * 16; qq += 256) {
        int bl = qq >> 4, kc = qq & 15;
        const ushort_t* src = pooled + ((size_t)(b0 + bl) * 300 + g) * 100 + kc * 8;
        uint2 lo = *(const uint2*)src;          // rows 200B apart: 8B-aligned
        uint2 hi = *(const uint2*)(src + 4);    // i>=100 spills into next row / zero pad (finite, x0 by W pad)
        int swz = kc ^ (bl & 7);
        *(uint4*)&pl[((bl * 16) + swz) * 8] = (uint4){lo.x, lo.y, hi.x, hi.y};
    }
    if (tid < 112) {
        float a2 = 0.f, c2 = 0.f, w2v = 0.f;
        if (tid < 100) {
            int qq = g * 100 + tid;
            a2 = g2[qq] * rsqrtf(v2[qq] + EPSf);
            c2 = (b1[qq] - m2[qq]) * a2 + be2[qq];
            w2v = W2[qq];
        }
        A2s[tid] = a2; C2s[tid] = c2; w2sl[tid] = w2v;
    }
    if (tid == 0) {
        float a3 = g3[g] * rsqrtf(v3[g] + EPSf);
        sA3 = a3; sC3 = (b2[g] - m3[g]) * a3 + be3[g];
    }
    __syncthreads();

    const int w = tid >> 6, lane = tid & 63;
    const int col = lane & 15, quad = lane >> 4;

    short8 bfr[7][4];                          // all B-frags cached (112 VGPR)
#pragma unroll
    for (int nt = 0; nt < 7; ++nt)
#pragma unroll
        for (int s = 0; s < 4; ++s) {
            uint4 t4 = *(const uint4*)&W1l[(((s * 4 + quad) * 112) + nt * 16 + col) * 8];
            bfr[nt][s] = __builtin_bit_cast(short8, t4);
        }

#pragma unroll
    for (int mi = 0; mi < 2; ++mi) {
        const int mt = w * 2 + mi;
        const int bl = mt * 16 + col;          // A row
        uint4 afr[4];
#pragma unroll
        for (int s = 0; s < 4; ++s) {
            int kc = s * 4 + quad;
            afr[s] = *(const uint4*)&pl[((bl * 16) + (kc ^ (bl & 7))) * 8];
        }
        float run0 = 0.f, run1 = 0.f, run2 = 0.f, run3 = 0.f;
#pragma unroll
        for (int nt = 0; nt < 7; ++nt) {
            floatx4 acc = {0.f, 0.f, 0.f, 0.f};
#pragma unroll
            for (int s = 0; s < 4; ++s)
                acc = __builtin_amdgcn_mfma_f32_16x16x32_bf16(
                    __builtin_bit_cast(short8, afr[s]), bfr[nt][s], acc, 0, 0, 0);
            const float a2v = A2s[nt * 16 + col], c2v = C2s[nt * 16 + col], w2v = w2sl[nt * 16 + col];
            run0 += fmaxf(fmaf(acc[0], a2v, c2v), 0.f) * w2v;
            run1 += fmaxf(fmaf(acc[1], a2v, c2v), 0.f) * w2v;
            run2 += fmaxf(fmaf(acc[2], a2v, c2v), 0.f) * w2v;
            run3 += fmaxf(fmaf(acc[3], a2v, c2v), 0.f) * w2v;
        }
#pragma unroll
        for (int m = 1; m <= 8; m <<= 1) {     // sum over the 16 h-cols
            run0 += __shfl_xor(run0, m, 64);
            run1 += __shfl_xor(run1, m, 64);
            run2 += __shfl_xor(run2, m, 64);
            run3 += __shfl_xor(run3, m, 64);
        }
        if (col == 0) {
            float4 o;
            o.x = fmaxf(fmaf(run0, sA3, sC3), 0.f);
            o.y = fmaxf(fmaf(run1, sA3, sC3), 0.f);
            o.z = fmaxf(fmaf(run2, sA3, sC3), 0.f);
            o.w = fmaxf(fmaf(run3, sA3, sC3), 0.f);
            *(float4*)&h2ws[g * 256 + b0 + mt * 16 + quad * 4] = o;
        }
    }
}

// ---------------- Stage 3: classifier ----------------
__global__ __launch_bounds__(64) void classifier_kernel(
    const float* __restrict__ h2ws, const float* __restrict__ cls_w,
    const float* __restrict__ cls_b, float* __restrict__ out) {
    const int b = blockIdx.x, t = threadIdx.x;
    float a0 = 0.f, a1 = 0.f;
    for (int gg = t; gg < 300; gg += 64) {
        float v = h2ws[gg * 256 + b];
        a0 = fmaf(v, cls_w[gg], a0);
        a1 = fmaf(v, cls_w[300 + gg], a1);
    }
#pragma unroll
    for (int off = 32; off; off >>= 1) {
        a0 += __shfl_down(a0, off);
        a1 += __shfl_down(a1, off);
    }
    if (t == 0) {
        out[b * 2 + 0] = a0 + cls_b[0];
        out[b * 2 + 1] = a1 + cls_b[1];
    }
}

extern "C" void kernel_launch(void* const* d_in, const int* in_sizes, int n_in,
                              void* d_out, int out_size, void* d_ws, size_t ws_size,
                              hipStream_t stream) {
    const float* x      = (const float*)d_in[0];
    const float* conv_w = (const float*)d_in[1];
    const float* conv_b = (const float*)d_in[2];
    const float* bn1_g  = (const float*)d_in[3];
    const float* bn1_b  = (const float*)d_in[4];
    const float* bn1_m  = (const float*)d_in[5];
    const float* bn1_v  = (const float*)d_in[6];
    const float* W1     = (const float*)d_in[7];
    const float* b1     = (const float*)d_in[8];
    const float* bn2_g  = (const float*)d_in[9];
    const float* bn2_b  = (const float*)d_in[10];
    const float* bn2_m  = (const float*)d_in[11];
    const float* bn2_v  = (const float*)d_in[12];
    const float* W2     = (const float*)d_in[13];
    const float* b2     = (const float*)d_in[14];
    const float* bn3_g  = (const float*)d_in[15];
    const float* bn3_b  = (const float*)d_in[16];
    const float* bn3_m  = (const float*)d_in[17];
    const float* bn3_v  = (const float*)d_in[18];
    const float* cls_w  = (const float*)d_in[19];
    const float* cls_b  = (const float*)d_in[20];

    char* wsb = (char*)d_ws;
    ushort_t* pooled = (ushort_t*)wsb;                   // 15,360,000 B + 256 B zero pad
    float*    h2ws   = (float*)(wsb + 15360512);         //    307,200 B

    conv_mfma<<<dim3(256, 2), 256, 0, stream>>>(
        x, conv_w, conv_b, bn1_g, bn1_b, bn1_m, bn1_v, pooled);

    mlp_mfma<<<dim3(608), 256, 0, stream>>>(
        pooled, W1, b1, bn2_g, bn2_b, bn2_m, bn2_v, W2, b2,
        bn3_g, bn3_b, bn3_m, bn3_v, h2ws);

    classifier_kernel<<<dim3(256), 64, 0, stream>>>(h2ws, cls_w, cls_b, (float*)d_out);
}

// Round 3
// 145.998 us; speedup vs baseline: 1.4782x; 1.1152x over previous
//
#include <hip/hip_runtime.h>

// ExplaiNN inference on MFMA (bf16 matrix cores, f32 accumulate). 4 kernels:
// prep_all:  conv_w -> Wc[kc][304][8] bf16; W1 -> W1b[g][kc][112][8] bf16 (B-frag layout).
//            (Restored: in-kernel W1 staging in mlp cost ~+16us vs prepped linear copy.)
// conv_mfma: implicit-GEMM conv + BN1 + ReLU + partial maxpool -> pool0/pool1 bf16.
//            d-SPLIT: 512 thr / 8 waves; wave w owns tile (w&3), d-half (w>>2).
//            Per-wave af[5][3] = 60 VGPR -> register-resident (af[10][3]=120 > 88 VGPR
//            forced per-gt LDS re-reads before; that was the 45us latency bound).
// mlp_mfma:  per-group GEMM + BN2/ReLU + W2-dot + BN3/ReLU -> h2ws[g][b].
//            Staging combines pool0/pool1 via u16 max (post-ReLU bf16 >= 0: monotone).
// classifier: h2 @ cls_w^T + cls_b -> out[256][2] f32.

typedef unsigned short ushort_t;
typedef short short8 __attribute__((ext_vector_type(8)));
typedef float floatx4 __attribute__((ext_vector_type(4)));

constexpr float EPSf = 1e-5f;

__device__ __forceinline__ ushort_t f2bf(float f) {
    unsigned u = __float_as_uint(f);
    unsigned r = (u + 0x7FFFu + ((u >> 16) & 1u)) >> 16;   // round-to-nearest-even
    return (ushort_t)r;
}

__device__ __forceinline__ unsigned maxu16x2(unsigned a, unsigned b) {
    unsigned lo = (a & 0xffffu) > (b & 0xffffu) ? (a & 0xffffu) : (b & 0xffffu);
    unsigned hi = (a >> 16) > (b >> 16) ? (a >> 16) : (b >> 16);
    return lo | (hi << 16);
}

// ---------------- prep: weight transforms ----------------
constexpr int WC_BLKS  = 114;    // 29,184 ushorts = 12*304*8
constexpr int W1B_BLKS = 4256;   // 8 xcd * 38 g * 14 blocks (3584 thr/g = 16kc*112h*2jj)
__global__ __launch_bounds__(256) void prep_all(
    const float* __restrict__ conv_w, const float* __restrict__ W1,
    ushort_t* __restrict__ Wc, ushort_t* __restrict__ W1b)
{
    const int blk = blockIdx.x, t = threadIdx.x;
    if (blk < WC_BLKS) {
        int idx = blk * 256 + t;                     // exact: 114*256 = 29,184
        int j = idx & 7, g = (idx >> 3) % 304, kc = idx / (304 * 8);
        int k = kc * 8 + j, c = k / 24, tt = k - c * 24;
        float v = (g < 300 && tt < 19) ? conv_w[g * 76 + c * 19 + tt] : 0.f;
        Wc[idx] = f2bf(v);
    } else {
        // W1b[g][kc][h][8]; blk&7 selects XCD-local g range (38 g per XCD slice)
        int blk2 = blk - WC_BLKS;
        int xcd = blk2 & 7, j = blk2 >> 3;
        int gl = j / 14, inner = j - gl * 14;
        int g = xcd * 38 + gl;
        if (g >= 300) return;
        int v = inner * 256 + t;                     // 0..3583
        int jj = v & 1, r = v >> 1;
        int h = r % 112, kc = r / 112;
        int i0 = kc * 8 + jj * 4;
        ushort4 o = make_ushort4(0, 0, 0, 0);
        if (h < 100 && i0 <= 96) {
            float4 w = *(const float4*)&W1[(size_t)g * 10000 + h * 100 + i0];
            o = make_ushort4(f2bf(w.x), f2bf(w.y), f2bf(w.z), f2bf(w.w));
        }
        *(ushort4*)&W1b[((size_t)(g * 16 + kc) * 112 + h) * 8 + jj * 4] = o;
    }
}

// ---------------- Stage 1: conv via MFMA, d-split across wave pairs ----------------
// Window q=0: p 0..51 (4 M-tiles), q=1: p 52..99 (3 M-tiles). X0 = x_pad origin of LDS window.
// C[m=p][n=g] = sum_k A[m][k] B[k][n]; A[m][(c,t)] = x_pad[c][10(p)+d+t]; max over d in half.
__global__ __launch_bounds__(512, 4) void conv_mfma(
    const float* __restrict__ x, const ushort_t* __restrict__ Wc,
    const float* __restrict__ conv_b, const float* __restrict__ g1, const float* __restrict__ be1,
    const float* __restrict__ m1, const float* __restrict__ v1,
    ushort_t* __restrict__ pool0, ushort_t* __restrict__ pool1)
{
    __shared__ ushort_t Wl[12 * 304 * 8];      // 58368 B, [kc][g][8]
    __shared__ ushort_t xl[16 * 552];          // 17664 B, [(phi*4+c)][552], phase-shifted copies
    __shared__ float A1s[304], B1s[304];       // total 78464 B -> 2 blocks/CU (16 waves/CU)

    const int tid = threadIdx.x;
    const int b = blockIdx.x, q = blockIdx.y;
    const int X0 = q * 520;                     // x_pad coordinate of xl[.][0]

    // zero the 256B pad after EACH partial buffer (mlp overreads <=54B past last row;
    // ws is NaN-poisoned and NaN*0 = NaN through the zero-weight MFMA lanes).
    if (b == 0 && q == 0 && tid < 32) {
        ushort_t* bufp = (tid & 16) ? pool1 : pool0;
        uint4 z = {0, 0, 0, 0};
        *(uint4*)&bufp[7680000 + (tid & 15) * 8] = z;
    }

    // stage x (f32 global) -> 4 phase copies bf16 in LDS; copy phi elem i = x_pad[X0+i+phi]
    for (int u = tid; u < 16 * 276; u += 512) { // uint = 2 bf16
        int iu = u % 276, r = u / 276;
        int c = r & 3, phi = r >> 2;
        int gi = X0 + 2 * iu + phi - 9;         // x index of low element
        const float* xb = x + b * 4000 + c * 1000;
        float v0 = ((unsigned)gi < 1000u) ? xb[gi] : 0.f;
        float v1_ = ((unsigned)(gi + 1) < 1000u) ? xb[gi + 1] : 0.f;
        ((unsigned*)xl)[u] = (unsigned)f2bf(v0) | ((unsigned)f2bf(v1_) << 16);
    }
    {   // weights: linear 16B copy of prepped Wc (L2-resident, conflict-free)
        const uint4* wsrc = (const uint4*)Wc;
        uint4* wdst = (uint4*)Wl;
        for (int i = tid; i < 3648; i += 512) wdst[i] = wsrc[i];
    }
    for (int i = tid; i < 304; i += 512) {
        if (i < 300) {
            float A = g1[i] * rsqrtf(v1[i] + EPSf);
            A1s[i] = A;
            B1s[i] = (conv_b[i] - m1[i]) * A + be1[i];
        } else { A1s[i] = 0.f; B1s[i] = 0.f; }
    }
    __syncthreads();

    const int w = tid >> 6, lane = tid & 63;
    const int tile = w & 3, dh = w >> 2;        // dh=0: d 0..4, dh=1: d 5..9
    if (q == 1 && tile == 3) return;            // 3 tiles in window 1; no barriers after this
    const int p0 = q ? (52 + tile * 16) : (tile * 16);
    const int pmax = q ? 99 : 51;
    const int row = lane & 15, quad = lane >> 4;
    const int p_r = p0 + row;
    const int prc = (p_r < pmax) ? p_r : pmax;  // clamp keeps LDS reads in window (rows masked at store)
    ushort_t* __restrict__ dstbuf = dh ? pool1 : pool0;

    // A fragments for this wave's 5 d-shifts: 15 x uint4 = 60 VGPR, register-resident.
    uint4 af[5][3];
#pragma unroll
    for (int s = 0; s < 3; ++s) {
        int k0 = s * 32 + quad * 8;
        int c = k0 / 24, t0 = k0 - c * 24;
        int base0 = 10 * prc + t0 - X0 + dh * 5; // local window coords, max 535 (q0) / 495 (q1)
#pragma unroll
        for (int dd = 0; dd < 5; ++dd) {
            int local = base0 + dd;
            int phi = local & 3, bi = local - phi;
            const ushort_t* p = &xl[(phi * 4 + c) * 552 + bi];  // 8B-aligned
            uint2 lo = *(const uint2*)p;
            uint2 hi = *(const uint2*)(p + 4);
            af[dd][s] = (uint4){lo.x, lo.y, hi.x, hi.y};
        }
    }

    for (int gt = 0; gt < 19; ++gt) {
        short8 bf[3];
#pragma unroll
        for (int s = 0; s < 3; ++s) {
            uint4 t4 = *(const uint4*)&Wl[(((s * 4 + quad) * 304) + gt * 16 + row) * 8];
            bf[s] = __builtin_bit_cast(short8, t4);
        }
        const float a1v = A1s[gt * 16 + row], b1v = B1s[gt * 16 + row];
        floatx4 mx = {0.f, 0.f, 0.f, 0.f};     // ReLU floor (valid per-half: both halves >= 0)
#pragma unroll
        for (int dd = 0; dd < 5; ++dd) {
            floatx4 acc = {0.f, 0.f, 0.f, 0.f};
#pragma unroll
            for (int s = 0; s < 3; ++s)
                acc = __builtin_amdgcn_mfma_f32_16x16x32_bf16(
                    __builtin_bit_cast(short8, af[dd][s]), bf[s], acc, 0, 0, 0);
#pragma unroll
            for (int r = 0; r < 4; ++r)
                mx[r] = fmaxf(mx[r], fmaf(acc[r], a1v, b1v));
        }
        const int g = gt * 16 + row;            // C col = lane&15
        const int pr0 = p0 + quad * 4;          // C rows = quad*4 + r
        if (g < 300 && pr0 + 3 <= pmax) {
            ushort4 o = make_ushort4(f2bf(mx[0]), f2bf(mx[1]), f2bf(mx[2]), f2bf(mx[3]));
            *(ushort4*)&dstbuf[((size_t)b * 300 + g) * 100 + pr0] = o;
        }
    }
}

// ---------------- Stage 2: grouped MLP via MFMA ----------------
// grid 608: blk&7 = XCD slice, 38 g each, 2 b-halves per g on the same slice.
__global__ __launch_bounds__(256, 2) void mlp_mfma(
    const ushort_t* __restrict__ pool0, const ushort_t* __restrict__ pool1,
    const ushort_t* __restrict__ W1b,
    const float* __restrict__ b1, const float* __restrict__ g2, const float* __restrict__ be2,
    const float* __restrict__ m2, const float* __restrict__ v2,
    const float* __restrict__ W2, const float* __restrict__ b2,
    const float* __restrict__ g3, const float* __restrict__ be3,
    const float* __restrict__ m3, const float* __restrict__ v3,
    float* __restrict__ h2ws)
{
    __shared__ ushort_t W1l[16 * 112 * 8];     // 28672 B, [kc][h][8]
    __shared__ ushort_t pl[128 * 128];         // 32768 B, [bl][chunk^(bl&7)][8]
    __shared__ float A2s[112], C2s[112], w2sl[112];
    __shared__ float sA3, sC3;

    const int tid = threadIdx.x;
    const int blk = blockIdx.x;
    const int xcd = blk & 7, j = blk >> 3;
    const int g = xcd * 38 + (j >> 1);
    if (g >= 300) return;
    const int b0 = (j & 1) * 128;

    {   // pure linear copy of prepped B-frag image (conflict-free)
        const uint4* src = (const uint4*)(W1b + (size_t)g * 14336);
        uint4* dst = (uint4*)W1l;
        for (int i = tid; i < 1792; i += 256) dst[i] = src[i];
    }
    for (int qq = tid; qq < 128 * 16; qq += 256) {
        int bl = qq >> 4, kc = qq & 15;
        size_t off = ((size_t)(b0 + bl) * 300 + g) * 100 + kc * 8;
        const ushort_t* sA = pool0 + off;       // rows 200B apart: 8B-aligned
        const ushort_t* sB = pool1 + off;       // i>=100 spills into next row / zero pad (finite)
        uint2 loA = *(const uint2*)sA, hiA = *(const uint2*)(sA + 4);
        uint2 loB = *(const uint2*)sB, hiB = *(const uint2*)(sB + 4);
        uint4 m;                                // combine d-halves: u16 max (post-ReLU bf16 >= 0)
        m.x = maxu16x2(loA.x, loB.x);
        m.y = maxu16x2(loA.y, loB.y);
        m.z = maxu16x2(hiA.x, hiB.x);
        m.w = maxu16x2(hiA.y, hiB.y);
        int swz = kc ^ (bl & 7);
        *(uint4*)&pl[((bl * 16) + swz) * 8] = m;
    }
    if (tid < 112) {
        float a2 = 0.f, c2 = 0.f, w2v = 0.f;
        if (tid < 100) {
            int qq = g * 100 + tid;
            a2 = g2[qq] * rsqrtf(v2[qq] + EPSf);
            c2 = (b1[qq] - m2[qq]) * a2 + be2[qq];
            w2v = W2[qq];
        }
        A2s[tid] = a2; C2s[tid] = c2; w2sl[tid] = w2v;
    }
    if (tid == 0) {
        float a3 = g3[g] * rsqrtf(v3[g] + EPSf);
        sA3 = a3; sC3 = (b2[g] - m3[g]) * a3 + be3[g];
    }
    __syncthreads();

    const int w = tid >> 6, lane = tid & 63;
    const int col = lane & 15, quad = lane >> 4;

    short8 bfr[7][4];                          // all B-frags cached (112 VGPR)
#pragma unroll
    for (int nt = 0; nt < 7; ++nt)
#pragma unroll
        for (int s = 0; s < 4; ++s) {
            uint4 t4 = *(const uint4*)&W1l[(((s * 4 + quad) * 112) + nt * 16 + col) * 8];
            bfr[nt][s] = __builtin_bit_cast(short8, t4);
        }

#pragma unroll
    for (int mi = 0; mi < 2; ++mi) {
        const int mt = w * 2 + mi;
        const int bl = mt * 16 + col;          // A row
        uint4 afr[4];
#pragma unroll
        for (int s = 0; s < 4; ++s) {
            int kc = s * 4 + quad;
            afr[s] = *(const uint4*)&pl[((bl * 16) + (kc ^ (bl & 7))) * 8];
        }
        float run0 = 0.f, run1 = 0.f, run2 = 0.f, run3 = 0.f;
#pragma unroll
        for (int nt = 0; nt < 7; ++nt) {
            floatx4 acc = {0.f, 0.f, 0.f, 0.f};
#pragma unroll
            for (int s = 0; s < 4; ++s)
                acc = __builtin_amdgcn_mfma_f32_16x16x32_bf16(
                    __builtin_bit_cast(short8, afr[s]), bfr[nt][s], acc, 0, 0, 0);
            const float a2v = A2s[nt * 16 + col], c2v = C2s[nt * 16 + col], w2v = w2sl[nt * 16 + col];
            run0 += fmaxf(fmaf(acc[0], a2v, c2v), 0.f) * w2v;
            run1 += fmaxf(fmaf(acc[1], a2v, c2v), 0.f) * w2v;
            run2 += fmaxf(fmaf(acc[2], a2v, c2v), 0.f) * w2v;
            run3 += fmaxf(fmaf(acc[3], a2v, c2v), 0.f) * w2v;
        }
#pragma unroll
        for (int m = 1; m <= 8; m <<= 1) {     // sum over the 16 h-cols
            run0 += __shfl_xor(run0, m, 64);
            run1 += __shfl_xor(run1, m, 64);
            run2 += __shfl_xor(run2, m, 64);
            run3 += __shfl_xor(run3, m, 64);
        }
        if (col == 0) {
            float4 o;
            o.x = fmaxf(fmaf(run0, sA3, sC3), 0.f);
            o.y = fmaxf(fmaf(run1, sA3, sC3), 0.f);
            o.z = fmaxf(fmaf(run2, sA3, sC3), 0.f);
            o.w = fmaxf(fmaf(run3, sA3, sC3), 0.f);
            *(float4*)&h2ws[g * 256 + b0 + mt * 16 + quad * 4] = o;
        }
    }
}

// ---------------- Stage 3: classifier ----------------
__global__ __launch_bounds__(64) void classifier_kernel(
    const float* __restrict__ h2ws, const float* __restrict__ cls_w,
    const float* __restrict__ cls_b, float* __restrict__ out) {
    const int b = blockIdx.x, t = threadIdx.x;
    float a0 = 0.f, a1 = 0.f;
    for (int gg = t; gg < 300; gg += 64) {
        float v = h2ws[gg * 256 + b];
        a0 = fmaf(v, cls_w[gg], a0);
        a1 = fmaf(v, cls_w[300 + gg], a1);
    }
#pragma unroll
    for (int off = 32; off; off >>= 1) {
        a0 += __shfl_down(a0, off);
        a1 += __shfl_down(a1, off);
    }
    if (t == 0) {
        out[b * 2 + 0] = a0 + cls_b[0];
        out[b * 2 + 1] = a1 + cls_b[1];
    }
}

extern "C" void kernel_launch(void* const* d_in, const int* in_sizes, int n_in,
                              void* d_out, int out_size, void* d_ws, size_t ws_size,
                              hipStream_t stream) {
    const float* x      = (const float*)d_in[0];
    const float* conv_w = (const float*)d_in[1];
    const float* conv_b = (const float*)d_in[2];
    const float* bn1_g  = (const float*)d_in[3];
    const float* bn1_b  = (const float*)d_in[4];
    const float* bn1_m  = (const float*)d_in[5];
    const float* bn1_v  = (const float*)d_in[6];
    const float* W1     = (const float*)d_in[7];
    const float* b1     = (const float*)d_in[8];
    const float* bn2_g  = (const float*)d_in[9];
    const float* bn2_b  = (const float*)d_in[10];
    const float* bn2_m  = (const float*)d_in[11];
    const float* bn2_v  = (const float*)d_in[12];
    const float* W2     = (const float*)d_in[13];
    const float* b2     = (const float*)d_in[14];
    const float* bn3_g  = (const float*)d_in[15];
    const float* bn3_b  = (const float*)d_in[16];
    const float* bn3_m  = (const float*)d_in[17];
    const float* bn3_v  = (const float*)d_in[18];
    const float* cls_w  = (const float*)d_in[19];
    const float* cls_b  = (const float*)d_in[20];

    char* wsb = (char*)d_ws;
    ushort_t* pool0 = (ushort_t*)(wsb);                  // 15,360,000 B + 256 B pad
    ushort_t* pool1 = (ushort_t*)(wsb + 15360512);       // 15,360,000 B + 256 B pad
    ushort_t* Wc    = (ushort_t*)(wsb + 30721024);       //     58,368 B
    ushort_t* W1b   = (ushort_t*)(wsb + 30779392);       //  8,601,600 B
    float*    h2ws  = (float*)  (wsb + 39380992);        //    307,200 B

    prep_all<<<dim3(WC_BLKS + W1B_BLKS), 256, 0, stream>>>(conv_w, W1, Wc, W1b);

    conv_mfma<<<dim3(256, 2), 512, 0, stream>>>(
        x, Wc, conv_b, bn1_g, bn1_b, bn1_m, bn1_v, pool0, pool1);

    mlp_mfma<<<dim3(608), 256, 0, stream>>>(
        pool0, pool1, W1b, b1, bn2_g, bn2_b, bn2_m, bn2_v, W2, b2,
        bn3_g, bn3_b, bn3_m, bn3_v, h2ws);

    classifier_kernel<<<dim3(256), 64, 0, stream>>>(h2ws, cls_w, cls_b, (float*)d_out);
}

// Round 5
// 145.919 us; speedup vs baseline: 1.4790x; 1.0005x over previous
//
#include <hip/hip_runtime.h>

// ExplaiNN inference on MFMA (bf16 matrix cores, f32 accumulate). 4 kernels:
// prep_all:  conv_w -> Wc[kc][304][8] bf16; W1 -> W1b[g][kc][112][8] bf16 (B-frag layout).
// conv_mfma: implicit-GEMM conv + BN1 + ReLU + partial maxpool -> pool0/pool1 bf16.
//            d-SPLIT: 512 thr / 8 waves; wave w owns tile (w&3), d-half (w>>2).
//            af[5][3] PINNED via per-component asm opaque-def: VGPR_Count=88 @ cap 256
//            (r2) proved the allocator rematerializes LDS fragment loads per gt
//            iteration by CHOICE; the pin forces residency -> 3 LDS reads/gt not 33.
//            (128-bit tied asm operands don't compile on hipcc -> pin .x/.y/.z/.w.)
// mlp_mfma:  per-group GEMM + BN2/ReLU + W2-dot + BN3/ReLU -> h2ws[g][b].
//            bfr[7][4] pinned for the same reason (112 VGPR, cap 256).
//            Staging combines pool0/pool1 via u16 max (post-ReLU bf16 >= 0: monotone).
// classifier: h2 @ cls_w^T + cls_b -> out[256][2] f32.

typedef unsigned short ushort_t;
typedef short short8 __attribute__((ext_vector_type(8)));
typedef float floatx4 __attribute__((ext_vector_type(4)));

constexpr float EPSf = 1e-5f;

__device__ __forceinline__ ushort_t f2bf(float f) {
    unsigned u = __float_as_uint(f);
    unsigned r = (u + 0x7FFFu + ((u >> 16) & 1u)) >> 16;   // round-to-nearest-even
    return (ushort_t)r;
}

__device__ __forceinline__ unsigned maxu16x2(unsigned a, unsigned b) {
    unsigned lo = (a & 0xffffu) > (b & 0xffffu) ? (a & 0xffffu) : (b & 0xffffu);
    unsigned hi = (a >> 16) > (b >> 16) ? (a >> 16) : (b >> 16);
    return lo | (hi << 16);
}

// opaque def of a uint4, component-wise (hipcc rejects tied 128-bit asm operands)
__device__ __forceinline__ void pin4(uint4& v) {
    asm volatile("" : "+v"(v.x), "+v"(v.y), "+v"(v.z), "+v"(v.w));
}

// ---------------- prep: weight transforms ----------------
constexpr int WC_BLKS  = 114;    // 29,184 ushorts = 12*304*8
constexpr int W1B_BLKS = 4256;   // 8 xcd * 38 g * 14 blocks (3584 thr/g = 16kc*112h*2jj)
__global__ __launch_bounds__(256) void prep_all(
    const float* __restrict__ conv_w, const float* __restrict__ W1,
    ushort_t* __restrict__ Wc, ushort_t* __restrict__ W1b)
{
    const int blk = blockIdx.x, t = threadIdx.x;
    if (blk < WC_BLKS) {
        int idx = blk * 256 + t;                     // exact: 114*256 = 29,184
        int j = idx & 7, g = (idx >> 3) % 304, kc = idx / (304 * 8);
        int k = kc * 8 + j, c = k / 24, tt = k - c * 24;
        float v = (g < 300 && tt < 19) ? conv_w[g * 76 + c * 19 + tt] : 0.f;
        Wc[idx] = f2bf(v);
    } else {
        // W1b[g][kc][h][8]; blk&7 selects XCD-local g range (38 g per XCD slice)
        int blk2 = blk - WC_BLKS;
        int xcd = blk2 & 7, j = blk2 >> 3;
        int gl = j / 14, inner = j - gl * 14;
        int g = xcd * 38 + gl;
        if (g >= 300) return;
        int v = inner * 256 + t;                     // 0..3583
        int jj = v & 1, r = v >> 1;
        int h = r % 112, kc = r / 112;
        int i0 = kc * 8 + jj * 4;
        ushort4 o = make_ushort4(0, 0, 0, 0);
        if (h < 100 && i0 <= 96) {
            float4 w = *(const float4*)&W1[(size_t)g * 10000 + h * 100 + i0];
            o = make_ushort4(f2bf(w.x), f2bf(w.y), f2bf(w.z), f2bf(w.w));
        }
        *(ushort4*)&W1b[((size_t)(g * 16 + kc) * 112 + h) * 8 + jj * 4] = o;
    }
}

// ---------------- Stage 1: conv via MFMA, d-split across wave pairs ----------------
// Window q=0: p 0..51 (4 M-tiles), q=1: p 52..99 (3 M-tiles). X0 = x_pad origin of LDS window.
// C[m=p][n=g] = sum_k A[m][k] B[k][n]; A[m][(c,t)] = x_pad[c][10(p)+d+t]; max over d in half.
__global__ __launch_bounds__(512, 4) void conv_mfma(
    const float* __restrict__ x, const ushort_t* __restrict__ Wc,
    const float* __restrict__ conv_b, const float* __restrict__ g1, const float* __restrict__ be1,
    const float* __restrict__ m1, const float* __restrict__ v1,
    ushort_t* __restrict__ pool0, ushort_t* __restrict__ pool1)
{
    __shared__ ushort_t Wl[12 * 304 * 8];      // 58368 B, [kc][g][8]
    __shared__ ushort_t xl[16 * 552];          // 17664 B, [(phi*4+c)][552], phase-shifted copies
    __shared__ float A1s[304], B1s[304];       // total 78464 B -> 2 blocks/CU (16 waves/CU)

    const int tid = threadIdx.x;
    const int b = blockIdx.x, q = blockIdx.y;
    const int X0 = q * 520;                     // x_pad coordinate of xl[.][0]

    // zero the 256B pad after EACH partial buffer (mlp overreads <=54B past last row;
    // ws is NaN-poisoned and NaN*0 = NaN through the zero-weight MFMA lanes).
    if (b == 0 && q == 0 && tid < 32) {
        ushort_t* bufp = (tid & 16) ? pool1 : pool0;
        uint4 z = {0, 0, 0, 0};
        *(uint4*)&bufp[7680000 + (tid & 15) * 8] = z;
    }

    // stage x (f32 global) -> 4 phase copies bf16 in LDS; copy phi elem i = x_pad[X0+i+phi]
    for (int u = tid; u < 16 * 276; u += 512) { // uint = 2 bf16
        int iu = u % 276, r = u / 276;
        int c = r & 3, phi = r >> 2;
        int gi = X0 + 2 * iu + phi - 9;         // x index of low element
        const float* xb = x + b * 4000 + c * 1000;
        float v0 = ((unsigned)gi < 1000u) ? xb[gi] : 0.f;
        float v1_ = ((unsigned)(gi + 1) < 1000u) ? xb[gi + 1] : 0.f;
        ((unsigned*)xl)[u] = (unsigned)f2bf(v0) | ((unsigned)f2bf(v1_) << 16);
    }
    {   // weights: linear 16B copy of prepped Wc (L2-resident, conflict-free)
        const uint4* wsrc = (const uint4*)Wc;
        uint4* wdst = (uint4*)Wl;
        for (int i = tid; i < 3648; i += 512) wdst[i] = wsrc[i];
    }
    for (int i = tid; i < 304; i += 512) {
        if (i < 300) {
            float A = g1[i] * rsqrtf(v1[i] + EPSf);
            A1s[i] = A;
            B1s[i] = (conv_b[i] - m1[i]) * A + be1[i];
        } else { A1s[i] = 0.f; B1s[i] = 0.f; }
    }
    __syncthreads();

    const int w = tid >> 6, lane = tid & 63;
    const int tile = w & 3, dh = w >> 2;        // dh=0: d 0..4, dh=1: d 5..9
    if (q == 1 && tile == 3) return;            // 3 tiles in window 1; no barriers after this
    const int p0 = q ? (52 + tile * 16) : (tile * 16);
    const int pmax = q ? 99 : 51;
    const int row = lane & 15, quad = lane >> 4;
    const int p_r = p0 + row;
    const int prc = (p_r < pmax) ? p_r : pmax;  // clamp keeps LDS reads in window (rows masked at store)
    ushort_t* __restrict__ dstbuf = dh ? pool1 : pool0;

    // A fragments for this wave's 5 d-shifts: 15 x uint4 = 60 VGPR.
    uint4 af[5][3];
#pragma unroll
    for (int s = 0; s < 3; ++s) {
        int k0 = s * 32 + quad * 8;
        int c = k0 / 24, t0 = k0 - c * 24;
        int base0 = 10 * prc + t0 - X0 + dh * 5; // local window coords, max 535 (q0) / 495 (q1)
#pragma unroll
        for (int dd = 0; dd < 5; ++dd) {
            int local = base0 + dd;
            int phi = local & 3, bi = local - phi;
            const ushort_t* p = &xl[(phi * 4 + c) * 552 + bi];  // 8B-aligned
            uint2 lo = *(const uint2*)p;
            uint2 hi = *(const uint2*)(p + 4);
            af[dd][s] = (uint4){lo.x, lo.y, hi.x, hi.y};
        }
    }
    // PIN: opaque volatile def per fragment — allocator cannot rematerialize the LDS
    // loads inside the gt loop (r2 evidence: VGPR=88 @ cap 256 => remat-by-choice).
#pragma unroll
    for (int dd = 0; dd < 5; ++dd)
#pragma unroll
        for (int s = 0; s < 3; ++s)
            pin4(af[dd][s]);

    for (int gt = 0; gt < 19; ++gt) {
        short8 bf[3];
#pragma unroll
        for (int s = 0; s < 3; ++s) {
            uint4 t4 = *(const uint4*)&Wl[(((s * 4 + quad) * 304) + gt * 16 + row) * 8];
            bf[s] = __builtin_bit_cast(short8, t4);
        }
        const float a1v = A1s[gt * 16 + row], b1v = B1s[gt * 16 + row];
        floatx4 mx = {0.f, 0.f, 0.f, 0.f};     // ReLU floor (valid per-half: both halves >= 0)
#pragma unroll
        for (int dd = 0; dd < 5; ++dd) {
            floatx4 acc = {0.f, 0.f, 0.f, 0.f};
#pragma unroll
            for (int s = 0; s < 3; ++s)
                acc = __builtin_amdgcn_mfma_f32_16x16x32_bf16(
                    __builtin_bit_cast(short8, af[dd][s]), bf[s], acc, 0, 0, 0);
#pragma unroll
            for (int r = 0; r < 4; ++r)
                mx[r] = fmaxf(mx[r], fmaf(acc[r], a1v, b1v));
        }
        const int g = gt * 16 + row;            // C col = lane&15
        const int pr0 = p0 + quad * 4;          // C rows = quad*4 + r
        if (g < 300 && pr0 + 3 <= pmax) {
            ushort4 o = make_ushort4(f2bf(mx[0]), f2bf(mx[1]), f2bf(mx[2]), f2bf(mx[3]));
            *(ushort4*)&dstbuf[((size_t)b * 300 + g) * 100 + pr0] = o;
        }
    }
}

// ---------------- Stage 2: grouped MLP via MFMA ----------------
// grid 608: blk&7 = XCD slice, 38 g each, 2 b-halves per g on the same slice.
__global__ __launch_bounds__(256, 2) void mlp_mfma(
    const ushort_t* __restrict__ pool0, const ushort_t* __restrict__ pool1,
    const ushort_t* __restrict__ W1b,
    const float* __restrict__ b1, const float* __restrict__ g2, const float* __restrict__ be2,
    const float* __restrict__ m2, const float* __restrict__ v2,
    const float* __restrict__ W2, const float* __restrict__ b2,
    const float* __restrict__ g3, const float* __restrict__ be3,
    const float* __restrict__ m3, const float* __restrict__ v3,
    float* __restrict__ h2ws)
{
    __shared__ ushort_t W1l[16 * 112 * 8];     // 28672 B, [kc][h][8]
    __shared__ ushort_t pl[128 * 128];         // 32768 B, [bl][chunk^(bl&7)][8]
    __shared__ float A2s[112], C2s[112], w2sl[112];
    __shared__ float sA3, sC3;

    const int tid = threadIdx.x;
    const int blk = blockIdx.x;
    const int xcd = blk & 7, j = blk >> 3;
    const int g = xcd * 38 + (j >> 1);
    if (g >= 300) return;
    const int b0 = (j & 1) * 128;

    {   // pure linear copy of prepped B-frag image (conflict-free)
        const uint4* src = (const uint4*)(W1b + (size_t)g * 14336);
        uint4* dst = (uint4*)W1l;
        for (int i = tid; i < 1792; i += 256) dst[i] = src[i];
    }
    for (int qq = tid; qq < 128 * 16; qq += 256) {
        int bl = qq >> 4, kc = qq & 15;
        size_t off = ((size_t)(b0 + bl) * 300 + g) * 100 + kc * 8;
        const ushort_t* sA = pool0 + off;       // rows 200B apart: 8B-aligned
        const ushort_t* sB = pool1 + off;       // i>=100 spills into next row / zero pad (finite)
        uint2 loA = *(const uint2*)sA, hiA = *(const uint2*)(sA + 4);
        uint2 loB = *(const uint2*)sB, hiB = *(const uint2*)(sB + 4);
        uint4 m;                                // combine d-halves: u16 max (post-ReLU bf16 >= 0)
        m.x = maxu16x2(loA.x, loB.x);
        m.y = maxu16x2(loA.y, loB.y);
        m.z = maxu16x2(hiA.x, hiB.x);
        m.w = maxu16x2(hiA.y, hiB.y);
        int swz = kc ^ (bl & 7);
        *(uint4*)&pl[((bl * 16) + swz) * 8] = m;
    }
    if (tid < 112) {
        float a2 = 0.f, c2 = 0.f, w2v = 0.f;
        if (tid < 100) {
            int qq = g * 100 + tid;
            a2 = g2[qq] * rsqrtf(v2[qq] + EPSf);
            c2 = (b1[qq] - m2[qq]) * a2 + be2[qq];
            w2v = W2[qq];
        }
        A2s[tid] = a2; C2s[tid] = c2; w2sl[tid] = w2v;
    }
    if (tid == 0) {
        float a3 = g3[g] * rsqrtf(v3[g] + EPSf);
        sA3 = a3; sC3 = (b2[g] - m3[g]) * a3 + be3[g];
    }
    __syncthreads();

    const int w = tid >> 6, lane = tid & 63;
    const int col = lane & 15, quad = lane >> 4;

    uint4 bfr[7][4];                           // all B-frags cached (112 VGPR), pinned below
#pragma unroll
    for (int nt = 0; nt < 7; ++nt)
#pragma unroll
        for (int s = 0; s < 4; ++s)
            bfr[nt][s] = *(const uint4*)&W1l[(((s * 4 + quad) * 112) + nt * 16 + col) * 8];
#pragma unroll
    for (int nt = 0; nt < 7; ++nt)
#pragma unroll
        for (int s = 0; s < 4; ++s)
            pin4(bfr[nt][s]);

#pragma unroll
    for (int mi = 0; mi < 2; ++mi) {
        const int mt = w * 2 + mi;
        const int bl = mt * 16 + col;          // A row
        uint4 afr[4];
#pragma unroll
        for (int s = 0; s < 4; ++s) {
            int kc = s * 4 + quad;
            afr[s] = *(const uint4*)&pl[((bl * 16) + (kc ^ (bl & 7))) * 8];
        }
        float run0 = 0.f, run1 = 0.f, run2 = 0.f, run3 = 0.f;
#pragma unroll
        for (int nt = 0; nt < 7; ++nt) {
            floatx4 acc = {0.f, 0.f, 0.f, 0.f};
#pragma unroll
            for (int s = 0; s < 4; ++s)
                acc = __builtin_amdgcn_mfma_f32_16x16x32_bf16(
                    __builtin_bit_cast(short8, afr[s]), __builtin_bit_cast(short8, bfr[nt][s]), acc, 0, 0, 0);
            const float a2v = A2s[nt * 16 + col], c2v = C2s[nt * 16 + col], w2v = w2sl[nt * 16 + col];
            run0 += fmaxf(fmaf(acc[0], a2v, c2v), 0.f) * w2v;
            run1 += fmaxf(fmaf(acc[1], a2v, c2v), 0.f) * w2v;
            run2 += fmaxf(fmaf(acc[2], a2v, c2v), 0.f) * w2v;
            run3 += fmaxf(fmaf(acc[3], a2v, c2v), 0.f) * w2v;
        }
#pragma unroll
        for (int m = 1; m <= 8; m <<= 1) {     // sum over the 16 h-cols
            run0 += __shfl_xor(run0, m, 64);
            run1 += __shfl_xor(run1, m, 64);
            run2 += __shfl_xor(run2, m, 64);
            run3 += __shfl_xor(run3, m, 64);
        }
        if (col == 0) {
            float4 o;
            o.x = fmaxf(fmaf(run0, sA3, sC3), 0.f);
            o.y = fmaxf(fmaf(run1, sA3, sC3), 0.f);
            o.z = fmaxf(fmaf(run2, sA3, sC3), 0.f);
            o.w = fmaxf(fmaf(run3, sA3, sC3), 0.f);
            *(float4*)&h2ws[g * 256 + b0 + mt * 16 + quad * 4] = o;
        }
    }
}

// ---------------- Stage 3: classifier ----------------
__global__ __launch_bounds__(64) void classifier_kernel(
    const float* __restrict__ h2ws, const float* __restrict__ cls_w,
    const float* __restrict__ cls_b, float* __restrict__ out) {
    const int b = blockIdx.x, t = threadIdx.x;
    float a0 = 0.f, a1 = 0.f;
    for (int gg = t; gg < 300; gg += 64) {
        float v = h2ws[gg * 256 + b];
        a0 = fmaf(v, cls_w[gg], a0);
        a1 = fmaf(v, cls_w[300 + gg], a1);
    }
#pragma unroll
    for (int off = 32; off; off >>= 1) {
        a0 += __shfl_down(a0, off);
        a1 += __shfl_down(a1, off);
    }
    if (t == 0) {
        out[b * 2 + 0] = a0 + cls_b[0];
        out[b * 2 + 1] = a1 + cls_b[1];
    }
}

extern "C" void kernel_launch(void* const* d_in, const int* in_sizes, int n_in,
                              void* d_out, int out_size, void* d_ws, size_t ws_size,
                              hipStream_t stream) {
    const float* x      = (const float*)d_in[0];
    const float* conv_w = (const float*)d_in[1];
    const float* conv_b = (const float*)d_in[2];
    const float* bn1_g  = (const float*)d_in[3];
    const float* bn1_b  = (const float*)d_in[4];
    const float* bn1_m  = (const float*)d_in[5];
    const float* bn1_v  = (const float*)d_in[6];
    const float* W1     = (const float*)d_in[7];
    const float* b1     = (const float*)d_in[8];
    const float* bn2_g  = (const float*)d_in[9];
    const float* bn2_b  = (const float*)d_in[10];
    const float* bn2_m  = (const float*)d_in[11];
    const float* bn2_v  = (const float*)d_in[12];
    const float* W2     = (const float*)d_in[13];
    const float* b2     = (const float*)d_in[14];
    const float* bn3_g  = (const float*)d_in[15];
    const float* bn3_b  = (const float*)d_in[16];
    const float* bn3_m  = (const float*)d_in[17];
    const float* bn3_v  = (const float*)d_in[18];
    const float* cls_w  = (const float*)d_in[19];
    const float* cls_b  = (const float*)d_in[20];

    char* wsb = (char*)d_ws;
    ushort_t* pool0 = (ushort_t*)(wsb);                  // 15,360,000 B + 256 B pad
    ushort_t* pool1 = (ushort_t*)(wsb + 15360512);       // 15,360,000 B + 256 B pad
    ushort_t* Wc    = (ushort_t*)(wsb + 30721024);       //     58,368 B
    ushort_t* W1b   = (ushort_t*)(wsb + 30779392);       //  8,601,600 B
    float*    h2ws  = (float*)  (wsb + 39380992);        //    307,200 B

    prep_all<<<dim3(WC_BLKS + W1B_BLKS), 256, 0, stream>>>(conv_w, W1, Wc, W1b);

    conv_mfma<<<dim3(256, 2), 512, 0, stream>>>(
        x, Wc, conv_b, bn1_g, bn1_b, bn1_m, bn1_v, pool0, pool1);

    mlp_mfma<<<dim3(608), 256, 0, stream>>>(
        pool0, pool1, W1b, b1, bn2_g, bn2_b, bn2_m, bn2_v, W2, b2,
        bn3_g, bn3_b, bn3_m, bn3_v, h2ws);

    classifier_kernel<<<dim3(256), 64, 0, stream>>>(h2ws, cls_w, cls_b, (float*)d_out);
}